// Round 2
// baseline (230.712 us; speedup 1.0000x reference)
//
#include <hip/hip_runtime.h>

#define NPOS   131072
#define KCB    512
#define DIM    64
#define CHUNK  128
#define P      66       // padded LDS row stride in floats
#define EPS    0.008f   // candidate screen: > 2x worst-case fp32 distance error

__global__ __launch_bounds__(256) void vq_kernel(
    const float* __restrict__ x, const float* __restrict__ emb,
    float* __restrict__ out_q, float* __restrict__ out_enc,
    float* __restrict__ out_dist, float* __restrict__ out_loss)
{
    __shared__ float xs[64 * P];        // x tile   [w][d]
    __shared__ float es[CHUNK * P];     // emb tile [k][d]
    __shared__ float xx_s[64];          // ||x_n||^2
    __shared__ float ee_s[CHUNK];       // ||e_k||^2 (per chunk)
    __shared__ int   enc_s[64];
    __shared__ float red_s[4];

    const int t   = threadIdx.x;
    const int bid = blockIdx.x;          // = b*64 + h
    const int tx  = t & 15;              // k-lane (16)
    const int ty  = t >> 4;              // n-group (16): rows ty*4..ty*4+3
    const int n_base = bid * 64;
    // x[b][d][h][w] flat: b*262144 + d*4096 + h*64 + w ; bid = b*64+h
    const size_t xbase = (size_t)(bid >> 6) * 262144 + (size_t)(bid & 63) * 64;

    // ---- stage x tile (coalesced: lanes sweep w) ----
    {
        const int w  = t & 63;
        const int d0 = t >> 6;
        #pragma unroll
        for (int it = 0; it < 16; ++it) {
            int d = d0 + it * 4;
            xs[w * P + d] = x[xbase + (size_t)d * 4096 + w];
        }
    }
    __syncthreads();
    if (t < 64) {
        float s = 0.f;
        #pragma unroll
        for (int d = 0; d < 64; ++d) { float v = xs[t * P + d]; s = fmaf(v, v, s); }
        xx_s[t] = s;
    }

    const float2* emb2 = (const float2*)emb;

    for (int kc = 0; kc < 4; ++kc) {
        __syncthreads();   // protect es/ee_s from previous chunk readers (covers xx_s on kc=0)
        // ---- stage codebook chunk (coalesced float2) ----
        #pragma unroll
        for (int it = 0; it < 16; ++it) {
            int idx = it * 256 + t;
            int r = idx >> 5, c2 = idx & 31;
            float2 v = emb2[(size_t)(kc * CHUNK + r) * 32 + c2];
            es[r * P + 2 * c2]     = v.x;
            es[r * P + 2 * c2 + 1] = v.y;
        }
        __syncthreads();
        if (t < CHUNK) {
            float s = 0.f;
            #pragma unroll
            for (int d = 0; d < 64; ++d) { float v = es[t * P + d]; s = fmaf(v, v, s); }
            ee_s[t] = s;
        }
        __syncthreads();

        // ---- register-tiled dot products: 4n x 8k ----
        float acc[4][8];
        #pragma unroll
        for (int i = 0; i < 4; ++i)
            #pragma unroll
            for (int j = 0; j < 8; ++j) acc[i][j] = 0.f;

        #pragma unroll 4
        for (int d = 0; d < 64; d += 2) {
            float2 xv[4], ev[8];
            #pragma unroll
            for (int i = 0; i < 4; ++i) xv[i] = *(const float2*)&xs[(ty * 4 + i) * P + d];
            #pragma unroll
            for (int j = 0; j < 8; ++j) ev[j] = *(const float2*)&es[(tx + 16 * j) * P + d];
            #pragma unroll
            for (int i = 0; i < 4; ++i)
                #pragma unroll
                for (int j = 0; j < 8; ++j) {
                    acc[i][j] = fmaf(xv[i].x, ev[j].x, acc[i][j]);
                    acc[i][j] = fmaf(xv[i].y, ev[j].y, acc[i][j]);
                }
        }

        // ---- finalize distances + store ----
        #pragma unroll
        for (int i = 0; i < 4; ++i) {
            int n = ty * 4 + i;
            float xxv = xx_s[n];
            #pragma unroll
            for (int j = 0; j < 8; ++j) {
                int klocal = tx + 16 * j;
                int k = kc * CHUNK + klocal;
                float dist = xxv + ee_s[klocal] - 2.f * acc[i][j];
                out_dist[(size_t)(n_base + n) * KCB + k] = dist;
            }
        }
    }

    __syncthreads();   // drains vmcnt: all dist stores complete & visible

    // ---- phase 2: argmin per row with fp64 refinement of near-ties ----
    // wave wv owns rows 16*wv..16*wv+15 (exactly the rows it wrote -> L1/L2 hot)
    {
        const int wv = t >> 6;
        const int ln = t & 63;
        #pragma unroll 1
        for (int rr = 0; rr < 16; ++rr) {
            const int row = wv * 16 + rr;
            const float* dp = out_dist + (size_t)(n_base + row) * KCB + ln * 8;
            float4 a = *(const float4*)dp;
            float4 b = *(const float4*)(dp + 4);
            float v[8] = {a.x, a.y, a.z, a.w, b.x, b.y, b.z, b.w};

            // lane-local first-min
            float m1 = v[0]; int i1 = 0;
            #pragma unroll
            for (int j = 1; j < 8; ++j) if (v[j] < m1) { m1 = v[j]; i1 = j; }
            float bv = m1; int bk = ln * 8 + i1;
            // wave argmin (first-index tie-break)
            #pragma unroll
            for (int m = 1; m < 64; m <<= 1) {
                float ov = __shfl_xor(bv, m, 64);
                int   ok = __shfl_xor(bk, m, 64);
                if (ov < bv || (ov == bv && ok < bk)) { bv = ov; bk = ok; }
            }

            // candidate screen
            const float thr = bv + EPS;
            int cnt = 0;
            #pragma unroll
            for (int j = 0; j < 8; ++j) cnt += (v[j] <= thr) ? 1 : 0;
            unsigned long long many = __ballot(cnt > 1);
            unsigned long long some = __ballot(cnt > 0);
            int enc = bk;
            if (many != 0ULL || __popcll(some) > 1) {
                // rare: >=2 candidates within EPS -> exact fp64 decision
                double bestv = 1e300; int bestk = 0x7fffffff;
                for (int j = 0; j < 8; ++j) {
                    if (v[j] <= thr) {
                        int k = ln * 8 + j;
                        double s = 0.0;
                        for (int d = 0; d < 64; ++d) {
                            double df = (double)xs[row * P + d] - (double)emb[k * 64 + d];
                            s += df * df;
                        }
                        if (s < bestv) { bestv = s; bestk = k; }  // ascending k, strict <
                    }
                }
                #pragma unroll
                for (int m = 1; m < 64; m <<= 1) {
                    double ov = __shfl_xor(bestv, m, 64);
                    int   ok  = __shfl_xor(bestk, m, 64);
                    if (ov < bestv || (ov == bestv && ok < bestk)) { bestv = ov; bestk = ok; }
                }
                enc = bestk;
            }
            if (ln == 0) {
                enc_s[row] = enc;
                out_enc[n_base + row] = (float)enc;
            }
        }
    }
    __syncthreads();

    // ---- quantized gather + commitment loss ----
    {
        const int w  = t & 63;
        const int dg = t >> 6;
        int e = enc_s[w];
        float lsum = 0.f;
        #pragma unroll
        for (int di = 0; di < 16; ++di) {
            int d = dg * 16 + di;
            float q = emb[e * 64 + d];                 // gather, L2-resident codebook
            out_q[xbase + (size_t)d * 4096 + w] = q;   // coalesced store
            float diff = q - xs[w * P + d];
            lsum = fmaf(diff, diff, lsum);
        }
        #pragma unroll
        for (int m = 32; m >= 1; m >>= 1) lsum += __shfl_down(lsum, m, 64);
        if ((t & 63) == 0) red_s[t >> 6] = lsum;
    }
    __syncthreads();
    if (t == 0) {
        float tot = red_s[0] + red_s[1] + red_s[2] + red_s[3];
        atomicAdd(out_loss, tot * (1.0f / 8388608.0f));
    }
}

extern "C" void kernel_launch(void* const* d_in, const int* in_sizes, int n_in,
                              void* d_out, int out_size, void* d_ws, size_t ws_size,
                              hipStream_t stream) {
    const float* x   = (const float*)d_in[0];   // [32,64,64,64]
    const float* emb = (const float*)d_in[1];   // [512,64]

    float* out_q    = (float*)d_out;            // 8388608
    float* out_enc  = out_q + 8388608;          // 131072
    float* out_dist = out_enc + 131072;         // 67108864
    float* out_loss = out_dist + 67108864;      // 1

    hipMemsetAsync(out_loss, 0, sizeof(float), stream);
    vq_kernel<<<NPOS / 64, 256, 0, stream>>>(x, emb, out_q, out_enc, out_dist, out_loss);
}